// Round 1
// baseline (1290.667 us; speedup 1.0000x reference)
//
#include <hip/hip_runtime.h>

#define THREADS 256

// ---------------------------------------------------------------------------
// ws layout (floats after a 64-byte header):
//   [int flag]            stride detector result (1 = int32 edges, 2 = int64)
//   dinv[N]               degree accum, then rsqrt(deg+1) in place
//   g1[N*64]              (X@W1)*dinv rows
//   acc1[N*64]            scatter accumulator layer 1
//   g2[N*32]
//   acc2[N*32]
// total ~77.2 MB
// ---------------------------------------------------------------------------

// Detect whether edge_index was stored as int64 (odd int32 words all zero)
// or int32. Writes stride (2 or 1) to *flag.
__global__ void k_detect(const int* __restrict__ e32, int* __restrict__ flag) {
    if (blockIdx.x == 0 && threadIdx.x == 0) {
        int st = 2;
        for (int i = 0; i < 64; ++i) {
            if (e32[2 * i + 1] != 0) { st = 1; break; }
        }
        *flag = st;
    }
}

__global__ __launch_bounds__(THREADS) void k_zero(float* __restrict__ p, int n) {
    int i = blockIdx.x * THREADS + threadIdx.x;
    if (i < n) p[i] = 0.0f;
}

// deg[dst] += 1 over all edges
__global__ __launch_bounds__(THREADS) void k_count(const int* __restrict__ eidx,
                                                   const int* __restrict__ flag,
                                                   int E, float* __restrict__ deg) {
    int st = *flag;
    int i = blockIdx.x * THREADS + threadIdx.x;
    int stride = gridDim.x * THREADS;
    for (int e = i; e < E; e += stride) {
        int d = eidx[(E + e) * st];
        atomicAdd(&deg[d], 1.0f);
    }
}

// dinv = rsqrt(deg + 1)   (+1 = self loop; always > 0)
__global__ __launch_bounds__(THREADS) void k_dinv(float* __restrict__ deg, int n) {
    int i = blockIdx.x * THREADS + threadIdx.x;
    if (i < n) deg[i] = rsqrtf(deg[i] + 1.0f);
}

// g1[r,c] = (x[r,:] @ W1[:,c]) * dinv[r];  acc1 = g1 (self-loop seed)
// thread = (row, col); wave covers one row's 64 cols. W1 (32 KB) in LDS.
__global__ __launch_bounds__(THREADS) void k_gemm1(const float* __restrict__ x,
                                                   const float* __restrict__ W1,
                                                   const float* __restrict__ dinv,
                                                   float* __restrict__ g1,
                                                   float* __restrict__ acc1, int N) {
    __shared__ float Wl[128 * 64];
    for (int i = threadIdx.x; i < 128 * 64; i += THREADS) Wl[i] = W1[i];
    __syncthreads();
    int c = threadIdx.x & 63;
    int rloc = threadIdx.x >> 6;  // 0..3
    for (int rb = blockIdx.x; rb * 4 < N; rb += gridDim.x) {
        int r = rb * 4 + rloc;
        if (r < N) {
            const float* xr = x + (long)r * 128;
            float acc = 0.0f;
#pragma unroll
            for (int k = 0; k < 128; ++k)
                acc = fmaf(xr[k], Wl[k * 64 + c], acc);
            float v = acc * dinv[r];
            g1[r * 64 + c] = v;
            acc1[r * 64 + c] = v;
        }
    }
}

// acc1[dst,:] += g1[src,:]   (64 lanes = 64 feats per edge, wave per edge)
__global__ __launch_bounds__(THREADS) void k_scatter1(const int* __restrict__ eidx,
                                                      const int* __restrict__ flag,
                                                      int E,
                                                      const float* __restrict__ g1,
                                                      float* __restrict__ acc1) {
    int st = *flag;
    int lane = threadIdx.x & 63;
    int w = (blockIdx.x * THREADS + threadIdx.x) >> 6;
    int nw = (gridDim.x * THREADS) >> 6;
    for (int e = w; e < E; e += nw) {
        int s = eidx[e * st];
        int d = eidx[(E + e) * st];
        atomicAdd(&acc1[d * 64 + lane], g1[s * 64 + lane]);
    }
}

// h1[r,k] = relu(dinv[r]*acc1[r,k] + b1[k]);  g2[r,c] = (h1[r,:]@W2[:,c])*dinv[r]
// acc2 = g2. thread = (row, col); 32 cols -> 8 rows per 256-thr block.
__global__ __launch_bounds__(THREADS) void k_gemm2(const float* __restrict__ acc1,
                                                   const float* __restrict__ W2,
                                                   const float* __restrict__ b1,
                                                   const float* __restrict__ dinv,
                                                   float* __restrict__ g2,
                                                   float* __restrict__ acc2, int N) {
    __shared__ float Wl[64 * 32];
    __shared__ float b1l[64];
    for (int i = threadIdx.x; i < 64 * 32; i += THREADS) Wl[i] = W2[i];
    if (threadIdx.x < 64) b1l[threadIdx.x] = b1[threadIdx.x];
    __syncthreads();
    int c = threadIdx.x & 31;
    int rloc = threadIdx.x >> 5;  // 0..7
    for (int rb = blockIdx.x; rb * 8 < N; rb += gridDim.x) {
        int r = rb * 8 + rloc;
        if (r < N) {
            const float* ar = acc1 + (long)r * 64;
            float dr = dinv[r];
            float acc = 0.0f;
#pragma unroll
            for (int k = 0; k < 64; ++k) {
                float h = fmaxf(fmaf(dr, ar[k], b1l[k]), 0.0f);
                acc = fmaf(h, Wl[k * 32 + c], acc);
            }
            float v = acc * dr;
            g2[r * 32 + c] = v;
            acc2[r * 32 + c] = v;
        }
    }
}

// acc2[dst,:] += g2[src,:]   (32 lanes per edge, 2 edges per wave)
__global__ __launch_bounds__(THREADS) void k_scatter2(const int* __restrict__ eidx,
                                                      const int* __restrict__ flag,
                                                      int E,
                                                      const float* __restrict__ g2,
                                                      float* __restrict__ acc2) {
    int st = *flag;
    int lane = threadIdx.x & 31;
    int g = (blockIdx.x * THREADS + threadIdx.x) >> 5;
    int ng = (gridDim.x * THREADS) >> 5;
    for (int e = g; e < E; e += ng) {
        int s = eidx[e * st];
        int d = eidx[(E + e) * st];
        atomicAdd(&acc2[d * 32 + lane], g2[s * 32 + lane]);
    }
}

// out[r,c] = dinv[r]*acc2[r,c] + b2[c]
__global__ __launch_bounds__(THREADS) void k_final(const float* __restrict__ acc2,
                                                   const float* __restrict__ dinv,
                                                   const float* __restrict__ b2,
                                                   float* __restrict__ out, int N) {
    int total = N * 32;
    int stride = gridDim.x * THREADS;
    for (int i = blockIdx.x * THREADS + threadIdx.x; i < total; i += stride)
        out[i] = dinv[i >> 5] * acc2[i] + b2[i & 31];
}

extern "C" void kernel_launch(void* const* d_in, const int* in_sizes, int n_in,
                              void* d_out, int out_size, void* d_ws, size_t ws_size,
                              hipStream_t stream) {
    const float* x  = (const float*)d_in[0];
    const int* eidx = (const int*)d_in[1];
    const float* W1 = (const float*)d_in[2];
    const float* b1 = (const float*)d_in[3];
    const float* W2 = (const float*)d_in[4];
    const float* b2 = (const float*)d_in[5];
    float* out = (float*)d_out;

    const int N = in_sizes[0] / 128;   // 100000
    const int E = in_sizes[1] / 2;     // 3200000

    int* flag   = (int*)d_ws;
    float* dinv = (float*)d_ws + 16;   // 64-byte offset
    float* g1   = dinv + N;
    float* acc1 = g1 + (long)N * 64;
    float* g2   = acc1 + (long)N * 64;
    float* acc2 = g2 + (long)N * 32;

    int nblkN  = (N + THREADS - 1) / THREADS;

    k_detect<<<1, 1, 0, stream>>>(eidx, flag);
    k_zero<<<nblkN, THREADS, 0, stream>>>(dinv, N);
    k_count<<<2048, THREADS, 0, stream>>>(eidx, flag, E, dinv);
    k_dinv<<<nblkN, THREADS, 0, stream>>>(dinv, N);
    k_gemm1<<<2048, THREADS, 0, stream>>>(x, W1, dinv, g1, acc1, N);
    k_scatter1<<<4096, THREADS, 0, stream>>>(eidx, flag, E, g1, acc1);
    k_gemm2<<<2048, THREADS, 0, stream>>>(acc1, W2, b1, dinv, g2, acc2, N);
    k_scatter2<<<4096, THREADS, 0, stream>>>(eidx, flag, E, g2, acc2);
    k_final<<<2048, THREADS, 0, stream>>>(acc2, dinv, b2, out, N);
}

// Round 2
// 853.284 us; speedup vs baseline: 1.5126x; 1.5126x over previous
//
#include <hip/hip_runtime.h>

#define THREADS 256
#define SCANB 1024

// ---------------------------------------------------------------------------
// Pipeline: detect -> zero deg -> count deg -> scan (CSR row_start) ->
//           fill csr_src -> dinv -> gemm1 (g1=(X@W1)*dinv) ->
//           agg1 (h1=relu(dinv*(g1[v]+sum g1[src])+b1)) ->
//           gemm2 (g2=(h1@W2)*dinv) -> agg2 (out=dinv*(g2[v]+sum)+b2)
// ---------------------------------------------------------------------------

__global__ void k_detect(const int* __restrict__ e32, int* __restrict__ flag) {
    if (blockIdx.x == 0 && threadIdx.x == 0) {
        int st = 2;
        for (int i = 0; i < 64; ++i)
            if (e32[2 * i + 1] != 0) { st = 1; break; }
        *flag = st;
    }
}

__global__ __launch_bounds__(THREADS) void k_zero_int(int* __restrict__ p, int n) {
    int i = blockIdx.x * THREADS + threadIdx.x;
    if (i < n) p[i] = 0;
}

__global__ __launch_bounds__(THREADS) void k_count(const int* __restrict__ eidx,
                                                   const int* __restrict__ flag,
                                                   int E, int* __restrict__ deg) {
    int st = *flag;
    int stride = gridDim.x * THREADS;
    for (int e = blockIdx.x * THREADS + threadIdx.x; e < E; e += stride) {
        int d = eidx[(E + e) * st];
        atomicAdd(&deg[d], 1);
    }
}

// block-level exclusive scan; per-block totals to partials
__global__ __launch_bounds__(SCANB) void k_scan1(const int* __restrict__ deg, int N,
                                                 int* __restrict__ row,
                                                 int* __restrict__ partials) {
    __shared__ int s[SCANB];
    int i = blockIdx.x * SCANB + threadIdx.x;
    int v = (i < N) ? deg[i] : 0;
    s[threadIdx.x] = v;
    __syncthreads();
    for (int off = 1; off < SCANB; off <<= 1) {
        int t = (threadIdx.x >= off) ? s[threadIdx.x - off] : 0;
        __syncthreads();
        s[threadIdx.x] += t;
        __syncthreads();
    }
    if (i < N) row[i] = s[threadIdx.x] - v;  // exclusive
    if (threadIdx.x == SCANB - 1) partials[blockIdx.x] = s[threadIdx.x];
}

// exclusive scan of partials (single block)
__global__ __launch_bounds__(THREADS) void k_scan2(int* __restrict__ partials, int np) {
    __shared__ int s[THREADS];
    int v = (threadIdx.x < np) ? partials[threadIdx.x] : 0;
    s[threadIdx.x] = v;
    __syncthreads();
    for (int off = 1; off < THREADS; off <<= 1) {
        int t = (threadIdx.x >= off) ? s[threadIdx.x - off] : 0;
        __syncthreads();
        s[threadIdx.x] += t;
        __syncthreads();
    }
    if (threadIdx.x < np) partials[threadIdx.x] = s[threadIdx.x] - v;
}

// add block offsets, init cursor, set row[N]
__global__ __launch_bounds__(THREADS) void k_scan3(int* __restrict__ row,
                                                   const int* __restrict__ partials,
                                                   const int* __restrict__ deg,
                                                   int* __restrict__ cursor, int N) {
    int i = blockIdx.x * THREADS + threadIdx.x;
    if (i < N) {
        int r = row[i] + partials[i / SCANB];
        row[i] = r;
        cursor[i] = r;
        if (i == N - 1) row[N] = r + deg[N - 1];
    }
}

__global__ __launch_bounds__(THREADS) void k_fill(const int* __restrict__ eidx,
                                                  const int* __restrict__ flag, int E,
                                                  int* __restrict__ cursor,
                                                  int* __restrict__ csr) {
    int st = *flag;
    int stride = gridDim.x * THREADS;
    for (int e = blockIdx.x * THREADS + threadIdx.x; e < E; e += stride) {
        int s = eidx[e * st];
        int d = eidx[(E + e) * st];
        int pos = atomicAdd(&cursor[d], 1);
        csr[pos] = s;
    }
}

__global__ __launch_bounds__(THREADS) void k_dinv(const int* __restrict__ deg,
                                                  float* __restrict__ dinv, int n) {
    int i = blockIdx.x * THREADS + threadIdx.x;
    if (i < n) dinv[i] = rsqrtf((float)deg[i] + 1.0f);
}

// g1[r,c] = (x[r,:] @ W1[:,c]) * dinv[r]
__global__ __launch_bounds__(THREADS) void k_gemm1(const float* __restrict__ x,
                                                   const float* __restrict__ W1,
                                                   const float* __restrict__ dinv,
                                                   float* __restrict__ g1, int N) {
    __shared__ float Wl[128 * 64];
    for (int i = threadIdx.x; i < 128 * 64; i += THREADS) Wl[i] = W1[i];
    __syncthreads();
    int c = threadIdx.x & 63;
    int rloc = threadIdx.x >> 6;  // 0..3
    for (int rb = blockIdx.x; rb * 4 < N; rb += gridDim.x) {
        int r = rb * 4 + rloc;
        if (r < N) {
            const float4* xr = (const float4*)(x + (size_t)r * 128);
            float acc = 0.0f;
#pragma unroll
            for (int k4 = 0; k4 < 32; ++k4) {
                float4 xv = xr[k4];
                acc = fmaf(xv.x, Wl[(k4 * 4 + 0) * 64 + c], acc);
                acc = fmaf(xv.y, Wl[(k4 * 4 + 1) * 64 + c], acc);
                acc = fmaf(xv.z, Wl[(k4 * 4 + 2) * 64 + c], acc);
                acc = fmaf(xv.w, Wl[(k4 * 4 + 3) * 64 + c], acc);
            }
            g1[(size_t)r * 64 + c] = acc * dinv[r];
        }
    }
}

// h1[v,:] = relu(dinv[v]*(g1[v,:] + sum_{src->v} g1[src,:]) + b1)
// one wave per node, 64 lanes = 64 feats
__global__ __launch_bounds__(THREADS) void k_agg1(const int* __restrict__ row,
                                                  const int* __restrict__ csr,
                                                  const float* __restrict__ g1,
                                                  const float* __restrict__ dinv,
                                                  const float* __restrict__ b1,
                                                  float* __restrict__ h1, int N) {
    int v = (blockIdx.x * THREADS + threadIdx.x) >> 6;
    if (v >= N) return;
    int lane = threadIdx.x & 63;
    int beg = row[v], end = row[v + 1];
    float sum = g1[(size_t)v * 64 + lane];
    int j = beg;
    int s_next = (j < end) ? csr[j] : 0;
    while (j < end) {
        int s_cur = s_next;
        ++j;
        if (j < end) s_next = csr[j];
        sum += g1[(size_t)s_cur * 64 + lane];
    }
    h1[(size_t)v * 64 + lane] = fmaxf(fmaf(dinv[v], sum, b1[lane]), 0.0f);
}

// g2[r,c] = (h1[r,:] @ W2[:,c]) * dinv[r]
__global__ __launch_bounds__(THREADS) void k_gemm2(const float* __restrict__ h1,
                                                   const float* __restrict__ W2,
                                                   const float* __restrict__ dinv,
                                                   float* __restrict__ g2, int N) {
    __shared__ float Wl[64 * 32];
    for (int i = threadIdx.x; i < 64 * 32; i += THREADS) Wl[i] = W2[i];
    __syncthreads();
    int c = threadIdx.x & 31;
    int rloc = threadIdx.x >> 5;  // 0..7
    for (int rb = blockIdx.x; rb * 8 < N; rb += gridDim.x) {
        int r = rb * 8 + rloc;
        if (r < N) {
            const float4* ar = (const float4*)(h1 + (size_t)r * 64);
            float acc = 0.0f;
#pragma unroll
            for (int k4 = 0; k4 < 16; ++k4) {
                float4 hv = ar[k4];
                acc = fmaf(hv.x, Wl[(k4 * 4 + 0) * 32 + c], acc);
                acc = fmaf(hv.y, Wl[(k4 * 4 + 1) * 32 + c], acc);
                acc = fmaf(hv.z, Wl[(k4 * 4 + 2) * 32 + c], acc);
                acc = fmaf(hv.w, Wl[(k4 * 4 + 3) * 32 + c], acc);
            }
            g2[(size_t)r * 32 + c] = acc * dinv[r];
        }
    }
}

// out[v,:] = dinv[v]*(g2[v,:] + sum_{src->v} g2[src,:]) + b2
// half-wave per node, 32 lanes = 32 feats
__global__ __launch_bounds__(THREADS) void k_agg2(const int* __restrict__ row,
                                                  const int* __restrict__ csr,
                                                  const float* __restrict__ g2,
                                                  const float* __restrict__ dinv,
                                                  const float* __restrict__ b2,
                                                  float* __restrict__ out, int N) {
    int v = (blockIdx.x * THREADS + threadIdx.x) >> 5;
    if (v >= N) return;
    int lane = threadIdx.x & 31;
    int beg = row[v], end = row[v + 1];
    float sum = g2[(size_t)v * 32 + lane];
    int j = beg;
    int s_next = (j < end) ? csr[j] : 0;
    while (j < end) {
        int s_cur = s_next;
        ++j;
        if (j < end) s_next = csr[j];
        sum += g2[(size_t)s_cur * 32 + lane];
    }
    out[(size_t)v * 32 + lane] = fmaf(dinv[v], sum, b2[lane]);
}

extern "C" void kernel_launch(void* const* d_in, const int* in_sizes, int n_in,
                              void* d_out, int out_size, void* d_ws, size_t ws_size,
                              hipStream_t stream) {
    const float* x  = (const float*)d_in[0];
    const int* eidx = (const int*)d_in[1];
    const float* W1 = (const float*)d_in[2];
    const float* b1 = (const float*)d_in[3];
    const float* W2 = (const float*)d_in[4];
    const float* b2 = (const float*)d_in[5];
    float* out = (float*)d_out;

    const int N = in_sizes[0] / 128;   // 100000
    const int E = in_sizes[1] / 2;     // 3200000

    // ws layout (4-byte units after 64-byte header)
    int*   flag     = (int*)d_ws;
    int*   deg      = (int*)d_ws + 16;
    int*   row      = deg + N;          // N+1
    int*   cursor   = row + N + 1;
    int*   partials = cursor + N;       // 128 slots
    int*   csr      = partials + 128;   // E
    float* dinv     = (float*)(csr + E);
    float* g1       = dinv + N;         // N*64
    float* h1       = g1 + (size_t)N * 64;  // N*64
    float* g2       = g1;               // alias: g1 dead after agg1

    int nblkN = (N + THREADS - 1) / THREADS;
    int nscan = (N + SCANB - 1) / SCANB;

    k_detect<<<1, 1, 0, stream>>>(eidx, flag);
    k_zero_int<<<nblkN, THREADS, 0, stream>>>(deg, N);
    k_count<<<2048, THREADS, 0, stream>>>(eidx, flag, E, deg);
    k_scan1<<<nscan, SCANB, 0, stream>>>(deg, N, row, partials);
    k_scan2<<<1, THREADS, 0, stream>>>(partials, nscan);
    k_scan3<<<nblkN, THREADS, 0, stream>>>(row, partials, deg, cursor, N);
    k_fill<<<2048, THREADS, 0, stream>>>(eidx, flag, E, cursor, csr);
    k_dinv<<<nblkN, THREADS, 0, stream>>>(deg, dinv, N);
    k_gemm1<<<2048, THREADS, 0, stream>>>(x, W1, dinv, g1, N);
    k_agg1<<<(N * 64 + THREADS - 1) / THREADS, THREADS, 0, stream>>>(row, csr, g1, dinv, b1, h1, N);
    k_gemm2<<<2048, THREADS, 0, stream>>>(h1, W2, dinv, g2, N);
    k_agg2<<<(N * 32 + THREADS - 1) / THREADS, THREADS, 0, stream>>>(row, csr, g2, dinv, b2, out, N);
}